// Round 2
// baseline (343.520 us; speedup 1.0000x reference)
//
#include <hip/hip_runtime.h>
#include <hip/hip_bf16.h>

// ProbAttention (Informer ProbSparse), b=4 h=8 L=4096 d=64, sample_k=n_top=41.
// I/O dtypes: q,k,v fp32; index int32 (jax x64 off => int64 decays to int32);
// output fp32. Internally kE uses bf16 MFMA (rounding << 3.3e-3 threshold).
//
// Pipeline:
//  kA: m[bh,q] = max_s(q.k_idx) - mean_s(q.k_idx)   (fp32 gather, 8 lanes/query)
//  kB: per-bh top-41 of m (iterative argmax in LDS)
//  kC1/kC2: v mean over L (fp32)
//  kD: broadcast vmean to all output rows (fp32)
//  kE: flash attention for the 41 top queries, bf16 MFMA 16x16x32,
//      split-L into 8 tiles of 512 keys -> partial (m,l,O) per tile
//  kF: merge 8 partials, scatter rows at top_q into output

#define NTOP 41
#define NPAD 48
#define TILES 8
#define TL 512
#define CH 64
#define NCHUNK (TL / CH)

typedef __attribute__((ext_vector_type(8))) short bf16x8;
typedef __attribute__((ext_vector_type(4))) float f32x4;

__device__ __forceinline__ unsigned short f2bf(float f) {
    unsigned int x = __float_as_uint(f);
    unsigned int r = (x + 0x7FFFu + ((x >> 16) & 1u)) >> 16;  // RNE
    return (unsigned short)r;
}
__device__ __forceinline__ unsigned int pack2(float lo, float hi) {
    return ((unsigned int)f2bf(hi) << 16) | f2bf(lo);
}

// ---------------- kA: sampled scores m = max - mean --------------------------
// 8 lanes per query (each lane = 8 floats of d via 2x float4). grid 4096 x 256.
__global__ __launch_bounds__(256) void kA_scores(const float* __restrict__ q,
                                                 const float* __restrict__ k,
                                                 const int* __restrict__ idxs,
                                                 float* __restrict__ m_out) {
    int t = threadIdx.x;
    int lane = t & 63, w = t >> 6;
    int g = lane >> 3, sl = lane & 7;
    long long qflat = (long long)blockIdx.x * 32 + w * 8 + g;  // 0..131071
    int bh = (int)(qflat >> 12);
    int qi = (int)(qflat & 4095);
    const float4* q4 = (const float4*)q;  // 16 float4 per row
    const float4* k4 = (const float4*)k;
    float4 qa = q4[qflat * 16 + sl * 2];
    float4 qb = q4[qflat * 16 + sl * 2 + 1];
    const int* irow = idxs + qi * 41;
    long long kbase = ((long long)bh << 12) * 16;
    float maxv = -1e30f, sum = 0.f;
    for (int s = 0; s < 41; s++) {
        int ki = irow[s] & 4095;
        float4 ka = k4[kbase + (long long)ki * 16 + sl * 2];
        float4 kb = k4[kbase + (long long)ki * 16 + sl * 2 + 1];
        float p = 0.f;
        p = fmaf(qa.x, ka.x, p); p = fmaf(qa.y, ka.y, p);
        p = fmaf(qa.z, ka.z, p); p = fmaf(qa.w, ka.w, p);
        p = fmaf(qb.x, kb.x, p); p = fmaf(qb.y, kb.y, p);
        p = fmaf(qb.z, kb.z, p); p = fmaf(qb.w, kb.w, p);
        p += __shfl_xor(p, 1);
        p += __shfl_xor(p, 2);
        p += __shfl_xor(p, 4);
        maxv = fmaxf(maxv, p);
        sum += p;
    }
    if (sl == 0) m_out[qflat] = maxv - sum * (1.0f / 41.0f);
}

// ---------------- kB: top-41 per (b,h) ---------------------------------------
__global__ __launch_bounds__(256) void kB_topk(const float* __restrict__ m_in,
                                               int* __restrict__ topq) {
    __shared__ float vals[4096];
    __shared__ float rv[4];
    __shared__ int ri[4];
    __shared__ int sel[NTOP];
    int bh = blockIdx.x, t = threadIdx.x;
    for (int i = t; i < 4096; i += 256) vals[i] = m_in[bh * 4096 + i];
    __syncthreads();
    for (int it = 0; it < NTOP; it++) {
        float best = -1e30f;
        int bidx = 0;
#pragma unroll
        for (int i = 0; i < 16; i++) {
            int id = i * 256 + t;
            float vv = vals[id];
            if (vv > best) { best = vv; bidx = id; }
        }
        for (int off = 32; off; off >>= 1) {
            float ov = __shfl_xor(best, off);
            int oi = __shfl_xor(bidx, off);
            if (ov > best || (ov == best && oi < bidx)) { best = ov; bidx = oi; }
        }
        if ((t & 63) == 0) { rv[t >> 6] = best; ri[t >> 6] = bidx; }
        __syncthreads();
        if (t == 0) {
            float bb = rv[0];
            int bi = ri[0];
#pragma unroll
            for (int u = 1; u < 4; u++)
                if (rv[u] > bb || (rv[u] == bb && ri[u] < bi)) { bb = rv[u]; bi = ri[u]; }
            sel[it] = bi;
            vals[bi] = -1e30f;
        }
        __syncthreads();
    }
    if (t < NTOP) topq[bh * NTOP + t] = sel[t];
}

// ---------------- kC: v mean over L ------------------------------------------
__global__ __launch_bounds__(256) void kC1(const float* __restrict__ v,
                                           float* __restrict__ vpart) {
    int bh = blockIdx.x, chn = blockIdx.y, t = threadIdx.x;
    int d = t & 63, r = t >> 6;
    long long base = ((long long)bh << 12) + chn * 256;
    float acc = 0.f;
    for (int i = 0; i < 64; i++) acc += v[(base + i * 4 + r) * 64 + d];
    __shared__ float red[256];
    red[t] = acc;
    __syncthreads();
    if (r == 0) vpart[(bh * 16 + chn) * 64 + d] = red[d] + red[64 + d] + red[128 + d] + red[192 + d];
}

__global__ void kC2(const float* __restrict__ vpart, float* __restrict__ vmean) {
    int bh = blockIdx.x, d = threadIdx.x;  // 64 threads
    float s = 0.f;
#pragma unroll
    for (int c = 0; c < 16; c++) s += vpart[(bh * 16 + c) * 64 + d];
    vmean[bh * 64 + d] = s * (1.0f / 4096.0f);
}

// ---------------- kD: broadcast vmean to whole output ------------------------
__global__ __launch_bounds__(256) void kD(const float* __restrict__ vmean,
                                          float* __restrict__ out) {
    long long g0 = (long long)blockIdx.x * 1024 + threadIdx.x;  // float4 units
    float4* out4 = (float4*)out;
#pragma unroll
    for (int i = 0; i < 4; i++) {
        long long g = g0 + i * 256;   // total 2,097,152 float4
        int bh = (int)(g >> 16);      // 65536 float4 per bh
        int d4 = (int)(g & 15);
        out4[g] = *(const float4*)(vmean + bh * 64 + d4 * 4);
    }
}

// ---------------- kE: flash attention for top queries (MFMA bf16) ------------
// grid (TILES, 32). Per block: 41(pad 48) queries x 512 keys, chunks of 64.
// LDS stride 72 ushorts; fp32 global loads packed to bf16 on store.
__global__ __launch_bounds__(256) void kE_attn(const float* __restrict__ q,
                                               const float* __restrict__ k,
                                               const float* __restrict__ v,
                                               const int* __restrict__ topq,
                                               float* __restrict__ part) {
    __shared__ unsigned short qs[NPAD * 72];
    __shared__ unsigned short kb[CH * 72];
    __shared__ unsigned short vt[64 * 72];   // V transposed: vt[d][j]
    __shared__ unsigned short pb[NPAD * 72]; // P (exp scores) in bf16
    __shared__ float sp[NPAD * 65];          // raw scores fp32
    __shared__ float m_i[NPAD], l_i[NPAD], fac[NPAD];

    const int t = threadIdx.x;
    const int tile = blockIdx.x, bh = blockIdx.y;
    const int lane = t & 63, w = t >> 6;
    const int c = lane & 15, quad = lane >> 4;
    const long long bhbase = ((long long)bh) << 12;

    const float4* q4f = (const float4*)q;  // 16 float4 per row
    const float4* k4f = (const float4*)k;
    const float4* v4f = (const float4*)v;

    // load Q rows (scaled by 1/8 == exact), pack to bf16
    for (int i = t; i < NTOP * 16; i += 256) {
        int n = i >> 4, oc = i & 15;
        int row = topq[bh * NTOP + n];
        float4 val = q4f[(bhbase + row) * 16 + oc];
        uint2 pk;
        pk.x = pack2(val.x * 0.125f, val.y * 0.125f);
        pk.y = pack2(val.z * 0.125f, val.w * 0.125f);
        *(uint2*)(&qs[n * 72 + oc * 4]) = pk;
    }
    for (int i = t; i < 7 * 72; i += 256) {  // zero pad rows 41..47
        qs[NTOP * 72 + i] = 0;
        pb[NTOP * 72 + i] = 0;
    }
    if (t < NPAD) { m_i[t] = -1e30f; l_i[t] = 0.f; fac[t] = 0.f; }

    f32x4 oacc[3];
#pragma unroll
    for (int qt = 0; qt < 3; qt++) oacc[qt] = (f32x4){0.f, 0.f, 0.f, 0.f};

    const int l0 = tile * TL;
    for (int ch = 0; ch < NCHUNK; ch++) {
        const int lb = l0 + ch * CH;
        __syncthreads();  // kb/vt safe to overwrite; qs/m_i visible (1st iter)
        // K chunk, row-major, fp32 -> bf16
#pragma unroll
        for (int i = 0; i < 4; i++) {
            int idx = i * 256 + t;
            int j = idx >> 4, oc = idx & 15;
            float4 val = k4f[(bhbase + lb + j) * 16 + oc];
            uint2 pk;
            pk.x = pack2(val.x, val.y);
            pk.y = pack2(val.z, val.w);
            *(uint2*)(&kb[j * 72 + oc * 4]) = pk;
        }
        // V chunk, transposed: lane handles rows 2jp,2jp+1, cols o*8..o*8+7
        {
            int jp = t & 31, o = t >> 5;
            float4 a0 = v4f[(bhbase + lb + 2 * jp) * 16 + o * 2];
            float4 a1 = v4f[(bhbase + lb + 2 * jp) * 16 + o * 2 + 1];
            float4 b0 = v4f[(bhbase + lb + 2 * jp + 1) * 16 + o * 2];
            float4 b1 = v4f[(bhbase + lb + 2 * jp + 1) * 16 + o * 2 + 1];
            float av[8] = {a0.x, a0.y, a0.z, a0.w, a1.x, a1.y, a1.z, a1.w};
            float bv[8] = {b0.x, b0.y, b0.z, b0.w, b1.x, b1.y, b1.z, b1.w};
#pragma unroll
            for (int e = 0; e < 8; e++)
                *(unsigned int*)(&vt[(o * 8 + e) * 72 + 2 * jp]) = pack2(av[e], bv[e]);
        }
        __syncthreads();
        // S = Qr @ K^T : wave w owns key-tile w
        {
            const bf16x8 bk0 = *(const bf16x8*)(&kb[(w * 16 + c) * 72 + quad * 8]);
            const bf16x8 bk1 = *(const bf16x8*)(&kb[(w * 16 + c) * 72 + quad * 8 + 32]);
#pragma unroll
            for (int qt = 0; qt < 3; qt++) {
                const bf16x8 a0 = *(const bf16x8*)(&qs[(qt * 16 + c) * 72 + quad * 8]);
                const bf16x8 a1 = *(const bf16x8*)(&qs[(qt * 16 + c) * 72 + quad * 8 + 32]);
                f32x4 s4 = (f32x4){0.f, 0.f, 0.f, 0.f};
                s4 = __builtin_amdgcn_mfma_f32_16x16x32_bf16(a0, bk0, s4, 0, 0, 0);
                s4 = __builtin_amdgcn_mfma_f32_16x16x32_bf16(a1, bk1, s4, 0, 0, 0);
#pragma unroll
                for (int r = 0; r < 4; r++)
                    sp[(qt * 16 + quad * 4 + r) * 65 + w * 16 + c] = s4[r];
            }
        }
        __syncthreads();
        // online softmax update (4 threads per query row)
        if (t < NTOP * 4) {
            int n = t >> 2, sub = t & 3;
            float rm = -1e30f;
#pragma unroll
            for (int j = 0; j < 16; j++) rm = fmaxf(rm, sp[n * 65 + sub * 16 + j]);
            rm = fmaxf(rm, __shfl_xor(rm, 1));
            rm = fmaxf(rm, __shfl_xor(rm, 2));
            float mo = m_i[n];
            float mn = fmaxf(mo, rm);
            float ssum = 0.f;
#pragma unroll
            for (int j = 0; j < 16; j += 2) {
                float e0 = __expf(sp[n * 65 + sub * 16 + j] - mn);
                float e1 = __expf(sp[n * 65 + sub * 16 + j + 1] - mn);
                ssum += e0 + e1;
                *(unsigned int*)(&pb[n * 72 + sub * 16 + j]) = pack2(e0, e1);
            }
            ssum += __shfl_xor(ssum, 1);
            ssum += __shfl_xor(ssum, 2);
            if (sub == 0) {
                float f = __expf(mo - mn);
                fac[n] = f;
                l_i[n] = l_i[n] * f + ssum;
                m_i[n] = mn;
            }
        }
        __syncthreads();
        // O = O*fac + P @ V : wave w owns d-tile w
        {
            const bf16x8 bv0 = *(const bf16x8*)(&vt[(w * 16 + c) * 72 + quad * 8]);
            const bf16x8 bv1 = *(const bf16x8*)(&vt[(w * 16 + c) * 72 + quad * 8 + 32]);
#pragma unroll
            for (int qt = 0; qt < 3; qt++) {
                const bf16x8 a0 = *(const bf16x8*)(&pb[(qt * 16 + c) * 72 + quad * 8]);
                const bf16x8 a1 = *(const bf16x8*)(&pb[(qt * 16 + c) * 72 + quad * 8 + 32]);
                f32x4 o = oacc[qt];
                o.x *= fac[qt * 16 + quad * 4 + 0];
                o.y *= fac[qt * 16 + quad * 4 + 1];
                o.z *= fac[qt * 16 + quad * 4 + 2];
                o.w *= fac[qt * 16 + quad * 4 + 3];
                o = __builtin_amdgcn_mfma_f32_16x16x32_bf16(a0, bv0, o, 0, 0, 0);
                o = __builtin_amdgcn_mfma_f32_16x16x32_bf16(a1, bv1, o, 0, 0, 0);
                oacc[qt] = o;
            }
        }
    }
    __syncthreads();
    // write partials: [bh][tile][n][2+64]
    long long pbase = ((long long)(bh * TILES + tile)) * NTOP * 66;
    if (t < NTOP) {
        part[pbase + t * 66 + 0] = m_i[t];
        part[pbase + t * 66 + 1] = l_i[t];
    }
#pragma unroll
    for (int qt = 0; qt < 3; qt++) {
#pragma unroll
        for (int r = 0; r < 4; r++) {
            int n = qt * 16 + quad * 4 + r;
            if (n < NTOP) part[pbase + (long long)n * 66 + 2 + w * 16 + c] = oacc[qt][r];
        }
    }
}

// ---------------- kF: merge tile partials, scatter rows ----------------------
__global__ __launch_bounds__(256) void kF_combine(const float* __restrict__ part,
                                                  const int* __restrict__ topq,
                                                  float* __restrict__ out) {
    int t = threadIdx.x;
    int bh = blockIdx.x;
    int n = blockIdx.y * 4 + (t >> 6);
    int d = t & 63;
    if (n >= NTOP) return;
    long long base = ((long long)(bh * TILES)) * NTOP * 66 + (long long)n * 66;
    const long long ts = (long long)NTOP * 66;
    float M = -1e30f;
#pragma unroll
    for (int tt = 0; tt < TILES; tt++) M = fmaxf(M, part[base + tt * ts]);
    float L = 0.f, acc = 0.f;
#pragma unroll
    for (int tt = 0; tt < TILES; tt++) {
        float mt = part[base + tt * ts];
        float wgt = __expf(mt - M);
        L += part[base + tt * ts + 1] * wgt;
        acc += part[base + tt * ts + 2 + d] * wgt;
    }
    int row = topq[bh * NTOP + n];
    out[(((long long)bh << 12) + row) * 64 + d] = acc / L;
}

// ---------------- launch -----------------------------------------------------
extern "C" void kernel_launch(void* const* d_in, const int* in_sizes, int n_in,
                              void* d_out, int out_size, void* d_ws, size_t ws_size,
                              hipStream_t stream) {
    const float* q = (const float*)d_in[0];
    const float* k = (const float*)d_in[1];
    const float* v = (const float*)d_in[2];
    const int* idxs = (const int*)d_in[3];
    float* out = (float*)d_out;

    char* ws = (char*)d_ws;
    float* ws_m = (float*)ws;                 // 131072 f  @ 0
    int* ws_topq = (int*)(ws + 524288);       // 1312 i
    float* ws_vpart = (float*)(ws + 532480);  // 32768 f
    float* ws_vmean = (float*)(ws + 663552);  // 2048 f
    float* ws_part = (float*)(ws + 671744);   // 692736 f (~2.8MB)

    kA_scores<<<4096, 256, 0, stream>>>(q, k, idxs, ws_m);
    kB_topk<<<32, 256, 0, stream>>>(ws_m, ws_topq);
    kC1<<<dim3(32, 16), 256, 0, stream>>>(v, ws_vpart);
    kC2<<<32, 64, 0, stream>>>(ws_vpart, ws_vmean);
    kD<<<2048, 256, 0, stream>>>(ws_vmean, out);
    kE_attn<<<dim3(TILES, 32), 256, 0, stream>>>(q, k, v, ws_topq, ws_part);
    kF_combine<<<dim3(32, 11), 256, 0, stream>>>(ws_part, ws_topq, out);
}

// Round 3
// 261.644 us; speedup vs baseline: 1.3129x; 1.3129x over previous
//
#include <hip/hip_runtime.h>
#include <hip/hip_bf16.h>

// ProbAttention (Informer ProbSparse), b=4 h=8 L=4096 d=64, sample_k=n_top=41.
// I/O: q,k,v fp32; index int32; output fp32. kE uses bf16 MFMA internally.
//
//  kA: m[bh,q] = max_s(q.k_idx) - mean_s(q.k_idx)  (fp32 gather, XCD-swizzled)
//  kB: per-bh exact top-41 via 2-pass radix select + exact tail argmax
//  kC1/kC2: v mean over L
//  kD: broadcast vmean to all output rows
//  kE: flash attention for top-41 queries, bf16 MFMA 16x16x32, 8 L-tiles
//  kF: merge partials, scatter rows at top_q

#define NTOP 41
#define NPAD 48
#define TILES 8
#define TL 512
#define CH 64
#define NCHUNK (TL / CH)
#define CAND_CAP 64

typedef __attribute__((ext_vector_type(8))) short bf16x8;
typedef __attribute__((ext_vector_type(4))) float f32x4;

__device__ __forceinline__ unsigned short f2bf(float f) {
    unsigned int x = __float_as_uint(f);
    unsigned int r = (x + 0x7FFFu + ((x >> 16) & 1u)) >> 16;  // RNE
    return (unsigned short)r;
}
__device__ __forceinline__ unsigned int pack2(float lo, float hi) {
    return ((unsigned int)f2bf(hi) << 16) | f2bf(lo);
}

// ---------------- kA: sampled scores m = max - mean --------------------------
// 8 lanes per query. XCD swizzle: blocks with blockIdx%8==i all map to XCD i
// and process a contiguous logical range => per-XCD L2 working set ~2MB.
__global__ __launch_bounds__(256) void kA_scores(const float* __restrict__ q,
                                                 const float* __restrict__ k,
                                                 const int* __restrict__ idxs,
                                                 float* __restrict__ m_out) {
    int t = threadIdx.x;
    int lane = t & 63, w = t >> 6;
    int g = lane >> 3, sl = lane & 7;
    int lb = ((blockIdx.x & 7) << 9) + (blockIdx.x >> 3);      // XCD swizzle
    long long qflat = (long long)lb * 32 + w * 8 + g;          // 0..131071
    int bh = (int)(qflat >> 12);
    int qi = (int)(qflat & 4095);
    const float4* q4 = (const float4*)q;  // 16 float4 per row
    const float4* k4 = (const float4*)k;
    float4 qa = q4[qflat * 16 + sl * 2];
    float4 qb = q4[qflat * 16 + sl * 2 + 1];
    const int* irow = idxs + qi * 41;
    long long kbase = ((long long)bh << 12) * 16;
    float maxv = -1e30f, sum = 0.f;
    for (int s = 0; s < 41; s++) {
        int ki = irow[s] & 4095;
        float4 ka = k4[kbase + (long long)ki * 16 + sl * 2];
        float4 kb = k4[kbase + (long long)ki * 16 + sl * 2 + 1];
        float p = 0.f;
        p = fmaf(qa.x, ka.x, p); p = fmaf(qa.y, ka.y, p);
        p = fmaf(qa.z, ka.z, p); p = fmaf(qa.w, ka.w, p);
        p = fmaf(qb.x, kb.x, p); p = fmaf(qb.y, kb.y, p);
        p = fmaf(qb.z, kb.z, p); p = fmaf(qb.w, kb.w, p);
        p += __shfl_xor(p, 1);
        p += __shfl_xor(p, 2);
        p += __shfl_xor(p, 4);
        maxv = fmaxf(maxv, p);
        sum += p;
    }
    if (sl == 0) m_out[qflat] = maxv - sum * (1.0f / 41.0f);
}

// ---------------- kB: exact top-41 per (b,h) via radix select ----------------
__global__ __launch_bounds__(256) void kB_topk(const float* __restrict__ m_in,
                                               int* __restrict__ topq) {
    __shared__ unsigned int uvals[4096];
    __shared__ unsigned int hist[256];
    __shared__ unsigned int scal[4];  // [0]=b1 [1]=c_above [2]=T [3]=cnt
    __shared__ int candIdx[CAND_CAP];
    __shared__ unsigned int candU[CAND_CAP];
    int bh = blockIdx.x, t = threadIdx.x;
    // load + order-preserving flip (float -> uint, ascending order preserved)
    for (int i = t; i < 4096; i += 256) {
        unsigned int b = __float_as_uint(m_in[bh * 4096 + i]);
        uvals[i] = (b & 0x80000000u) ? ~b : (b | 0x80000000u);
    }
    hist[t] = 0;
    __syncthreads();
    for (int i = t; i < 4096; i += 256) atomicAdd(&hist[uvals[i] >> 24], 1u);
    __syncthreads();
    if (t == 0) {
        unsigned int cum = 0, b1 = 0, ca = 0;
        for (int j = 255; j >= 0; j--) {
            if (cum + hist[j] >= 41u) { b1 = (unsigned)j; ca = cum; break; }
            cum += hist[j];
        }
        scal[0] = b1; scal[1] = ca;
    }
    __syncthreads();
    unsigned int b1 = scal[0];
    hist[t] = 0;
    __syncthreads();
    for (int i = t; i < 4096; i += 256)
        if ((uvals[i] >> 24) == b1) atomicAdd(&hist[(uvals[i] >> 16) & 255u], 1u);
    __syncthreads();
    if (t == 0) {
        unsigned int cum = scal[1], b2 = 0;
        for (int j = 255; j >= 0; j--) {
            if (cum + hist[j] >= 41u) { b2 = (unsigned)j; break; }
            cum += hist[j];
        }
        scal[2] = (b1 << 24) | (b2 << 16);
        scal[3] = 0;
    }
    __syncthreads();
    unsigned int T = scal[2];
    for (int i = t; i < 4096; i += 256) {
        unsigned int u = uvals[i];
        if (u >= T) {
            unsigned int pos = atomicAdd(&scal[3], 1u);
            if (pos < CAND_CAP) { candIdx[pos] = i; candU[pos] = u; }
        }
    }
    __syncthreads();
    // exact top-41 among <=64 candidates (full value compare, low-index ties)
    if (t < 64) {
        int n = (int)min(scal[3], (unsigned)CAND_CAP);
        unsigned int myU = (t < n) ? candU[t] : 0u;
        int myI = (t < n) ? candIdx[t] : 0x7fffffff;
        for (int it = 0; it < NTOP; it++) {
            unsigned int bu = myU;
            int bi = myI;
            for (int off = 32; off; off >>= 1) {
                unsigned int ou = __shfl_xor(bu, off);
                int oi = __shfl_xor(bi, off);
                if (ou > bu || (ou == bu && oi < bi)) { bu = ou; bi = oi; }
            }
            if (t == 0) topq[bh * NTOP + it] = bi;
            if (myI == bi) { myU = 0u; myI = 0x7fffffff; }
        }
    }
}

// ---------------- kC: v mean over L ------------------------------------------
__global__ __launch_bounds__(256) void kC1(const float* __restrict__ v,
                                           float* __restrict__ vpart) {
    int bh = blockIdx.x, chn = blockIdx.y, t = threadIdx.x;
    int d = t & 63, r = t >> 6;
    long long base = ((long long)bh << 12) + chn * 256;
    float acc = 0.f;
    for (int i = 0; i < 64; i++) acc += v[(base + i * 4 + r) * 64 + d];
    __shared__ float red[256];
    red[t] = acc;
    __syncthreads();
    if (r == 0) vpart[(bh * 16 + chn) * 64 + d] = red[d] + red[64 + d] + red[128 + d] + red[192 + d];
}

__global__ void kC2(const float* __restrict__ vpart, float* __restrict__ vmean) {
    int bh = blockIdx.x, d = threadIdx.x;  // 64 threads
    float s = 0.f;
#pragma unroll
    for (int c = 0; c < 16; c++) s += vpart[(bh * 16 + c) * 64 + d];
    vmean[bh * 64 + d] = s * (1.0f / 4096.0f);
}

// ---------------- kD: broadcast vmean to whole output ------------------------
__global__ __launch_bounds__(256) void kD(const float* __restrict__ vmean,
                                          float* __restrict__ out) {
    long long g0 = (long long)blockIdx.x * 1024 + threadIdx.x;  // float4 units
    float4* out4 = (float4*)out;
#pragma unroll
    for (int i = 0; i < 4; i++) {
        long long g = g0 + i * 256;   // total 2,097,152 float4
        int bh = (int)(g >> 16);      // 65536 float4 per bh
        int d4 = (int)(g & 15);
        out4[g] = *(const float4*)(vmean + bh * 64 + d4 * 4);
    }
}

// ---------------- kE: flash attention for top queries (MFMA bf16) ------------
__global__ __launch_bounds__(256) void kE_attn(const float* __restrict__ q,
                                               const float* __restrict__ k,
                                               const float* __restrict__ v,
                                               const int* __restrict__ topq,
                                               float* __restrict__ part) {
    __shared__ unsigned short qs[NPAD * 72];
    __shared__ unsigned short kb[CH * 72];
    __shared__ unsigned short vt[64 * 72];   // V transposed: vt[d][j]
    __shared__ unsigned short pb[NPAD * 72]; // P (exp scores) in bf16
    __shared__ float sp[NPAD * 65];          // raw scores fp32
    __shared__ float m_i[NPAD], l_i[NPAD], fac[NPAD];

    const int t = threadIdx.x;
    const int tile = blockIdx.x, bh = blockIdx.y;
    const int lane = t & 63, w = t >> 6;
    const int c = lane & 15, quad = lane >> 4;
    const long long bhbase = ((long long)bh) << 12;

    const float4* q4f = (const float4*)q;
    const float4* k4f = (const float4*)k;
    const float4* v4f = (const float4*)v;

    for (int i = t; i < NTOP * 16; i += 256) {
        int n = i >> 4, oc = i & 15;
        int row = topq[bh * NTOP + n];
        float4 val = q4f[(bhbase + row) * 16 + oc];
        uint2 pk;
        pk.x = pack2(val.x * 0.125f, val.y * 0.125f);
        pk.y = pack2(val.z * 0.125f, val.w * 0.125f);
        *(uint2*)(&qs[n * 72 + oc * 4]) = pk;
    }
    for (int i = t; i < 7 * 72; i += 256) {
        qs[NTOP * 72 + i] = 0;
        pb[NTOP * 72 + i] = 0;
    }
    if (t < NPAD) { m_i[t] = -1e30f; l_i[t] = 0.f; fac[t] = 0.f; }

    f32x4 oacc[3];
#pragma unroll
    for (int qt = 0; qt < 3; qt++) oacc[qt] = (f32x4){0.f, 0.f, 0.f, 0.f};

    const int l0 = tile * TL;
    for (int ch = 0; ch < NCHUNK; ch++) {
        const int lb = l0 + ch * CH;
        __syncthreads();
#pragma unroll
        for (int i = 0; i < 4; i++) {
            int idx = i * 256 + t;
            int j = idx >> 4, oc = idx & 15;
            float4 val = k4f[(bhbase + lb + j) * 16 + oc];
            uint2 pk;
            pk.x = pack2(val.x, val.y);
            pk.y = pack2(val.z, val.w);
            *(uint2*)(&kb[j * 72 + oc * 4]) = pk;
        }
        {
            int jp = t & 31, o = t >> 5;
            float4 a0 = v4f[(bhbase + lb + 2 * jp) * 16 + o * 2];
            float4 a1 = v4f[(bhbase + lb + 2 * jp) * 16 + o * 2 + 1];
            float4 b0 = v4f[(bhbase + lb + 2 * jp + 1) * 16 + o * 2];
            float4 b1 = v4f[(bhbase + lb + 2 * jp + 1) * 16 + o * 2 + 1];
            float av[8] = {a0.x, a0.y, a0.z, a0.w, a1.x, a1.y, a1.z, a1.w};
            float bv[8] = {b0.x, b0.y, b0.z, b0.w, b1.x, b1.y, b1.z, b1.w};
#pragma unroll
            for (int e = 0; e < 8; e++)
                *(unsigned int*)(&vt[(o * 8 + e) * 72 + 2 * jp]) = pack2(av[e], bv[e]);
        }
        __syncthreads();
        {
            const bf16x8 bk0 = *(const bf16x8*)(&kb[(w * 16 + c) * 72 + quad * 8]);
            const bf16x8 bk1 = *(const bf16x8*)(&kb[(w * 16 + c) * 72 + quad * 8 + 32]);
#pragma unroll
            for (int qt = 0; qt < 3; qt++) {
                const bf16x8 a0 = *(const bf16x8*)(&qs[(qt * 16 + c) * 72 + quad * 8]);
                const bf16x8 a1 = *(const bf16x8*)(&qs[(qt * 16 + c) * 72 + quad * 8 + 32]);
                f32x4 s4 = (f32x4){0.f, 0.f, 0.f, 0.f};
                s4 = __builtin_amdgcn_mfma_f32_16x16x32_bf16(a0, bk0, s4, 0, 0, 0);
                s4 = __builtin_amdgcn_mfma_f32_16x16x32_bf16(a1, bk1, s4, 0, 0, 0);
#pragma unroll
                for (int r = 0; r < 4; r++)
                    sp[(qt * 16 + quad * 4 + r) * 65 + w * 16 + c] = s4[r];
            }
        }
        __syncthreads();
        if (t < NTOP * 4) {
            int n = t >> 2, sub = t & 3;
            float rm = -1e30f;
#pragma unroll
            for (int j = 0; j < 16; j++) rm = fmaxf(rm, sp[n * 65 + sub * 16 + j]);
            rm = fmaxf(rm, __shfl_xor(rm, 1));
            rm = fmaxf(rm, __shfl_xor(rm, 2));
            float mo = m_i[n];
            float mn = fmaxf(mo, rm);
            float ssum = 0.f;
#pragma unroll
            for (int j = 0; j < 16; j += 2) {
                float e0 = __expf(sp[n * 65 + sub * 16 + j] - mn);
                float e1 = __expf(sp[n * 65 + sub * 16 + j + 1] - mn);
                ssum += e0 + e1;
                *(unsigned int*)(&pb[n * 72 + sub * 16 + j]) = pack2(e0, e1);
            }
            ssum += __shfl_xor(ssum, 1);
            ssum += __shfl_xor(ssum, 2);
            if (sub == 0) {
                float f = __expf(mo - mn);
                fac[n] = f;
                l_i[n] = l_i[n] * f + ssum;
                m_i[n] = mn;
            }
        }
        __syncthreads();
        {
            const bf16x8 bv0 = *(const bf16x8*)(&vt[(w * 16 + c) * 72 + quad * 8]);
            const bf16x8 bv1 = *(const bf16x8*)(&vt[(w * 16 + c) * 72 + quad * 8 + 32]);
#pragma unroll
            for (int qt = 0; qt < 3; qt++) {
                const bf16x8 a0 = *(const bf16x8*)(&pb[(qt * 16 + c) * 72 + quad * 8]);
                const bf16x8 a1 = *(const bf16x8*)(&pb[(qt * 16 + c) * 72 + quad * 8 + 32]);
                f32x4 o = oacc[qt];
                o.x *= fac[qt * 16 + quad * 4 + 0];
                o.y *= fac[qt * 16 + quad * 4 + 1];
                o.z *= fac[qt * 16 + quad * 4 + 2];
                o.w *= fac[qt * 16 + quad * 4 + 3];
                o = __builtin_amdgcn_mfma_f32_16x16x32_bf16(a0, bv0, o, 0, 0, 0);
                o = __builtin_amdgcn_mfma_f32_16x16x32_bf16(a1, bv1, o, 0, 0, 0);
                oacc[qt] = o;
            }
        }
    }
    __syncthreads();
    long long pbase = ((long long)(bh * TILES + tile)) * NTOP * 66;
    if (t < NTOP) {
        part[pbase + t * 66 + 0] = m_i[t];
        part[pbase + t * 66 + 1] = l_i[t];
    }
#pragma unroll
    for (int qt = 0; qt < 3; qt++) {
#pragma unroll
        for (int r = 0; r < 4; r++) {
            int n = qt * 16 + quad * 4 + r;
            if (n < NTOP) part[pbase + (long long)n * 66 + 2 + w * 16 + c] = oacc[qt][r];
        }
    }
}

// ---------------- kF: merge tile partials, scatter rows ----------------------
__global__ __launch_bounds__(256) void kF_combine(const float* __restrict__ part,
                                                  const int* __restrict__ topq,
                                                  float* __restrict__ out) {
    int t = threadIdx.x;
    int bh = blockIdx.x;
    int n = blockIdx.y * 4 + (t >> 6);
    int d = t & 63;
    if (n >= NTOP) return;
    long long base = ((long long)(bh * TILES)) * NTOP * 66 + (long long)n * 66;
    const long long ts = (long long)NTOP * 66;
    float M = -1e30f;
#pragma unroll
    for (int tt = 0; tt < TILES; tt++) M = fmaxf(M, part[base + tt * ts]);
    float L = 0.f, acc = 0.f;
#pragma unroll
    for (int tt = 0; tt < TILES; tt++) {
        float mt = part[base + tt * ts];
        float wgt = __expf(mt - M);
        L += part[base + tt * ts + 1] * wgt;
        acc += part[base + tt * ts + 2 + d] * wgt;
    }
    int row = topq[bh * NTOP + n];
    out[(((long long)bh << 12) + row) * 64 + d] = acc / L;
}

// ---------------- launch -----------------------------------------------------
extern "C" void kernel_launch(void* const* d_in, const int* in_sizes, int n_in,
                              void* d_out, int out_size, void* d_ws, size_t ws_size,
                              hipStream_t stream) {
    const float* q = (const float*)d_in[0];
    const float* k = (const float*)d_in[1];
    const float* v = (const float*)d_in[2];
    const int* idxs = (const int*)d_in[3];
    float* out = (float*)d_out;

    char* ws = (char*)d_ws;
    float* ws_m = (float*)ws;                 // 131072 f  @ 0
    int* ws_topq = (int*)(ws + 524288);       // 1312 i
    float* ws_vpart = (float*)(ws + 532480);  // 32768 f
    float* ws_vmean = (float*)(ws + 663552);  // 2048 f
    float* ws_part = (float*)(ws + 671744);   // 692736 f (~2.8MB)

    kA_scores<<<4096, 256, 0, stream>>>(q, k, idxs, ws_m);
    kB_topk<<<32, 256, 0, stream>>>(ws_m, ws_topq);
    kC1<<<dim3(32, 16), 256, 0, stream>>>(v, ws_vpart);
    kC2<<<32, 64, 0, stream>>>(ws_vpart, ws_vmean);
    kD<<<2048, 256, 0, stream>>>(ws_vmean, out);
    kE_attn<<<dim3(TILES, 32), 256, 0, stream>>>(q, k, v, ws_topq, ws_part);
    kF_combine<<<dim3(32, 11), 256, 0, stream>>>(ws_part, ws_topq, out);
}

// Round 4
// 252.090 us; speedup vs baseline: 1.3627x; 1.0379x over previous
//
#include <hip/hip_runtime.h>
#include <hip/hip_bf16.h>

// ProbAttention (Informer ProbSparse), b=4 h=8 L=4096 d=64, sample_k=n_top=41.
// I/O: q,k,v fp32; index int32; output fp32. kE uses bf16 MFMA internally.
//
//  kA: m[bh,q] = max_s(q.k_idx) - mean_s(q.k_idx)
//      (XCD-swizzled, idx staged in LDS, 4-wide software-pipelined gather)
//  kB: per-bh exact top-41 via 2-pass radix select + exact tail argmax
//  kC1: v partial sums over L
//  kD: finish v mean + broadcast to all output rows
//  kE: flash attention for top-41 queries, bf16 MFMA 16x16x32, TILES L-tiles
//  kF: merge partials, scatter rows at top_q

#define NTOP 41
#define NPAD 48
#define CH 64
#define CAND_CAP 64

typedef __attribute__((ext_vector_type(8))) short bf16x8;
typedef __attribute__((ext_vector_type(4))) float f32x4;

__device__ __forceinline__ unsigned short f2bf(float f) {
    unsigned int x = __float_as_uint(f);
    unsigned int r = (x + 0x7FFFu + ((x >> 16) & 1u)) >> 16;  // RNE
    return (unsigned short)r;
}
__device__ __forceinline__ unsigned int pack2(float lo, float hi) {
    return ((unsigned int)f2bf(hi) << 16) | f2bf(lo);
}
__device__ __forceinline__ float dot8(const float4& qa, const float4& qb,
                                      const float4& ka, const float4& kb) {
    float p = 0.f;
    p = fmaf(qa.x, ka.x, p); p = fmaf(qa.y, ka.y, p);
    p = fmaf(qa.z, ka.z, p); p = fmaf(qa.w, ka.w, p);
    p = fmaf(qb.x, kb.x, p); p = fmaf(qb.y, kb.y, p);
    p = fmaf(qb.z, kb.z, p); p = fmaf(qb.w, kb.w, p);
    return p;
}
__device__ __forceinline__ float red8(float p) {
    p += __shfl_xor(p, 1);
    p += __shfl_xor(p, 2);
    p += __shfl_xor(p, 4);
    return p;
}

// ---------------- kA: sampled scores m = max - mean --------------------------
// 8 lanes/query. XCD swizzle keeps each bh's K slice in one XCD's L2.
// Sample indices staged in LDS; gather loop unrolled x4 for MLP.
__global__ __launch_bounds__(256) void kA_scores(const float* __restrict__ q,
                                                 const float* __restrict__ k,
                                                 const int* __restrict__ idxs,
                                                 float* __restrict__ m_out) {
    __shared__ int sidx[32 * 41];
    int t = threadIdx.x;
    int lane = t & 63, w = t >> 6;
    int g = lane >> 3, sl = lane & 7;
    int lb = ((blockIdx.x & 7) << 9) + (blockIdx.x >> 3);      // XCD swizzle
    long long qflat = (long long)lb * 32 + w * 8 + g;          // 0..131071
    int bh = (int)(qflat >> 12);
    int qi0 = (lb * 32) & 4095;
    for (int i = t; i < 32 * 41; i += 256)
        sidx[i] = idxs[(long long)qi0 * 41 + i] & 4095;
    const float4* q4 = (const float4*)q;  // 16 float4 per row
    const float4* k4 = (const float4*)k;
    float4 qa = q4[qflat * 16 + sl * 2];
    float4 qb = q4[qflat * 16 + sl * 2 + 1];
    long long kbase = ((long long)bh << 12) * 16;
    __syncthreads();
    const int* irow = sidx + (w * 8 + g) * 41;
    float maxv = -1e30f, sum = 0.f;
#pragma unroll 2
    for (int g4 = 0; g4 < 10; g4++) {
        int ki0 = irow[g4 * 4 + 0], ki1 = irow[g4 * 4 + 1];
        int ki2 = irow[g4 * 4 + 2], ki3 = irow[g4 * 4 + 3];
        float4 ka0 = k4[kbase + (long long)ki0 * 16 + sl * 2];
        float4 kb0 = k4[kbase + (long long)ki0 * 16 + sl * 2 + 1];
        float4 ka1 = k4[kbase + (long long)ki1 * 16 + sl * 2];
        float4 kb1 = k4[kbase + (long long)ki1 * 16 + sl * 2 + 1];
        float4 ka2 = k4[kbase + (long long)ki2 * 16 + sl * 2];
        float4 kb2 = k4[kbase + (long long)ki2 * 16 + sl * 2 + 1];
        float4 ka3 = k4[kbase + (long long)ki3 * 16 + sl * 2];
        float4 kb3 = k4[kbase + (long long)ki3 * 16 + sl * 2 + 1];
        float p0 = red8(dot8(qa, qb, ka0, kb0));
        float p1 = red8(dot8(qa, qb, ka1, kb1));
        float p2 = red8(dot8(qa, qb, ka2, kb2));
        float p3 = red8(dot8(qa, qb, ka3, kb3));
        maxv = fmaxf(maxv, fmaxf(fmaxf(p0, p1), fmaxf(p2, p3)));
        sum += (p0 + p1) + (p2 + p3);
    }
    {   // remainder sample 40
        int ki = irow[40];
        float4 ka = k4[kbase + (long long)ki * 16 + sl * 2];
        float4 kb = k4[kbase + (long long)ki * 16 + sl * 2 + 1];
        float p = red8(dot8(qa, qb, ka, kb));
        maxv = fmaxf(maxv, p);
        sum += p;
    }
    if (sl == 0) m_out[qflat] = maxv - sum * (1.0f / 41.0f);
}

// ---------------- kB: exact top-41 per (b,h) via radix select ----------------
__global__ __launch_bounds__(256) void kB_topk(const float* __restrict__ m_in,
                                               int* __restrict__ topq) {
    __shared__ unsigned int uvals[4096];
    __shared__ unsigned int hist[256];
    __shared__ unsigned int scal[4];
    __shared__ int candIdx[CAND_CAP];
    __shared__ unsigned int candU[CAND_CAP];
    int bh = blockIdx.x, t = threadIdx.x;
    for (int i = t; i < 4096; i += 256) {
        unsigned int b = __float_as_uint(m_in[bh * 4096 + i]);
        uvals[i] = (b & 0x80000000u) ? ~b : (b | 0x80000000u);
    }
    hist[t] = 0;
    __syncthreads();
    for (int i = t; i < 4096; i += 256) atomicAdd(&hist[uvals[i] >> 24], 1u);
    __syncthreads();
    if (t == 0) {
        unsigned int cum = 0, b1 = 0, ca = 0;
        for (int j = 255; j >= 0; j--) {
            if (cum + hist[j] >= 41u) { b1 = (unsigned)j; ca = cum; break; }
            cum += hist[j];
        }
        scal[0] = b1; scal[1] = ca;
    }
    __syncthreads();
    unsigned int b1 = scal[0];
    hist[t] = 0;
    __syncthreads();
    for (int i = t; i < 4096; i += 256)
        if ((uvals[i] >> 24) == b1) atomicAdd(&hist[(uvals[i] >> 16) & 255u], 1u);
    __syncthreads();
    if (t == 0) {
        unsigned int cum = scal[1], b2 = 0;
        for (int j = 255; j >= 0; j--) {
            if (cum + hist[j] >= 41u) { b2 = (unsigned)j; break; }
            cum += hist[j];
        }
        scal[2] = (b1 << 24) | (b2 << 16);
        scal[3] = 0;
    }
    __syncthreads();
    unsigned int T = scal[2];
    for (int i = t; i < 4096; i += 256) {
        unsigned int u = uvals[i];
        if (u >= T) {
            unsigned int pos = atomicAdd(&scal[3], 1u);
            if (pos < CAND_CAP) { candIdx[pos] = i; candU[pos] = u; }
        }
    }
    __syncthreads();
    if (t < 64) {
        int n = (int)min(scal[3], (unsigned)CAND_CAP);
        unsigned int myU = (t < n) ? candU[t] : 0u;
        int myI = (t < n) ? candIdx[t] : 0x7fffffff;
        for (int it = 0; it < NTOP; it++) {
            unsigned int bu = myU;
            int bi = myI;
            for (int off = 32; off; off >>= 1) {
                unsigned int ou = __shfl_xor(bu, off);
                int oi = __shfl_xor(bi, off);
                if (ou > bu || (ou == bu && oi < bi)) { bu = ou; bi = oi; }
            }
            if (t == 0) topq[bh * NTOP + it] = bi;
            if (myI == bi) { myU = 0u; myI = 0x7fffffff; }
        }
    }
}

// ---------------- kC1: v partial sums ----------------------------------------
__global__ __launch_bounds__(256) void kC1(const float* __restrict__ v,
                                           float* __restrict__ vpart) {
    int bh = blockIdx.x, chn = blockIdx.y, t = threadIdx.x;
    int d = t & 63, r = t >> 6;
    long long base = ((long long)bh << 12) + chn * 256;
    float acc = 0.f;
    for (int i = 0; i < 64; i++) acc += v[(base + i * 4 + r) * 64 + d];
    __shared__ float red[256];
    red[t] = acc;
    __syncthreads();
    if (r == 0) vpart[(bh * 16 + chn) * 64 + d] = red[d] + red[64 + d] + red[128 + d] + red[192 + d];
}

// ---------------- kD: finish mean + broadcast to whole output ----------------
__global__ __launch_bounds__(256) void kD(const float* __restrict__ vpart,
                                          float* __restrict__ out) {
    __shared__ __align__(16) float vm[64];
    int t = threadIdx.x;
    int bh = blockIdx.x >> 6;  // 64 blocks per bh
    if (t < 64) {
        float s = 0.f;
#pragma unroll
        for (int c = 0; c < 16; c++) s += vpart[(bh * 16 + c) * 64 + t];
        vm[t] = s * (1.0f / 4096.0f);
    }
    __syncthreads();
    long long g0 = (long long)blockIdx.x * 1024 + t;  // float4 units
    float4* out4 = (float4*)out;
#pragma unroll
    for (int i = 0; i < 4; i++) {
        long long gg = g0 + i * 256;
        int d4 = (int)(gg & 15);
        out4[gg] = *(const float4*)(&vm[d4 * 4]);
    }
}

// ---------------- kE: flash attention for top queries (MFMA bf16) ------------
// grid (tiles, 32); tl keys per tile, chunks of 64.
__global__ __launch_bounds__(256) void kE_attn(const float* __restrict__ q,
                                               const float* __restrict__ k,
                                               const float* __restrict__ v,
                                               const int* __restrict__ topq,
                                               float* __restrict__ part, int tl) {
    __shared__ unsigned short qs[NPAD * 72];
    __shared__ unsigned short kb[CH * 72];
    __shared__ unsigned short vt[64 * 72];   // V transposed: vt[d][j]
    __shared__ unsigned short pb[NPAD * 72]; // P (exp scores) in bf16
    __shared__ float sp[NPAD * 65];          // raw scores fp32
    __shared__ float m_i[NPAD], l_i[NPAD], fac[NPAD];

    const int t = threadIdx.x;
    const int tile = blockIdx.x, bh = blockIdx.y;
    const int tiles = gridDim.x;
    const int lane = t & 63, w = t >> 6;
    const int c = lane & 15, quad = lane >> 4;
    const long long bhbase = ((long long)bh) << 12;

    const float4* q4f = (const float4*)q;
    const float4* k4f = (const float4*)k;
    const float4* v4f = (const float4*)v;

    for (int i = t; i < NTOP * 16; i += 256) {
        int n = i >> 4, oc = i & 15;
        int row = topq[bh * NTOP + n];
        float4 val = q4f[(bhbase + row) * 16 + oc];
        uint2 pk;
        pk.x = pack2(val.x * 0.125f, val.y * 0.125f);
        pk.y = pack2(val.z * 0.125f, val.w * 0.125f);
        *(uint2*)(&qs[n * 72 + oc * 4]) = pk;
    }
    for (int i = t; i < 7 * 72; i += 256) {
        qs[NTOP * 72 + i] = 0;
        pb[NTOP * 72 + i] = 0;
    }
    if (t < NPAD) { m_i[t] = -1e30f; l_i[t] = 0.f; fac[t] = 0.f; }

    f32x4 oacc[3];
#pragma unroll
    for (int qt = 0; qt < 3; qt++) oacc[qt] = (f32x4){0.f, 0.f, 0.f, 0.f};

    const int l0 = tile * tl;
    const int nchunk = tl >> 6;
    for (int ch = 0; ch < nchunk; ch++) {
        const int lb = l0 + ch * CH;
        __syncthreads();
#pragma unroll
        for (int i = 0; i < 4; i++) {
            int idx = i * 256 + t;
            int j = idx >> 4, oc = idx & 15;
            float4 val = k4f[(bhbase + lb + j) * 16 + oc];
            uint2 pk;
            pk.x = pack2(val.x, val.y);
            pk.y = pack2(val.z, val.w);
            *(uint2*)(&kb[j * 72 + oc * 4]) = pk;
        }
        {
            int jp = t & 31, o = t >> 5;
            float4 a0 = v4f[(bhbase + lb + 2 * jp) * 16 + o * 2];
            float4 a1 = v4f[(bhbase + lb + 2 * jp) * 16 + o * 2 + 1];
            float4 b0 = v4f[(bhbase + lb + 2 * jp + 1) * 16 + o * 2];
            float4 b1 = v4f[(bhbase + lb + 2 * jp + 1) * 16 + o * 2 + 1];
            float av[8] = {a0.x, a0.y, a0.z, a0.w, a1.x, a1.y, a1.z, a1.w};
            float bv[8] = {b0.x, b0.y, b0.z, b0.w, b1.x, b1.y, b1.z, b1.w};
#pragma unroll
            for (int e = 0; e < 8; e++)
                *(unsigned int*)(&vt[(o * 8 + e) * 72 + 2 * jp]) = pack2(av[e], bv[e]);
        }
        __syncthreads();
        {
            const bf16x8 bk0 = *(const bf16x8*)(&kb[(w * 16 + c) * 72 + quad * 8]);
            const bf16x8 bk1 = *(const bf16x8*)(&kb[(w * 16 + c) * 72 + quad * 8 + 32]);
#pragma unroll
            for (int qt = 0; qt < 3; qt++) {
                const bf16x8 a0 = *(const bf16x8*)(&qs[(qt * 16 + c) * 72 + quad * 8]);
                const bf16x8 a1 = *(const bf16x8*)(&qs[(qt * 16 + c) * 72 + quad * 8 + 32]);
                f32x4 s4 = (f32x4){0.f, 0.f, 0.f, 0.f};
                s4 = __builtin_amdgcn_mfma_f32_16x16x32_bf16(a0, bk0, s4, 0, 0, 0);
                s4 = __builtin_amdgcn_mfma_f32_16x16x32_bf16(a1, bk1, s4, 0, 0, 0);
#pragma unroll
                for (int r = 0; r < 4; r++)
                    sp[(qt * 16 + quad * 4 + r) * 65 + w * 16 + c] = s4[r];
            }
        }
        __syncthreads();
        if (t < NTOP * 4) {
            int n = t >> 2, sub = t & 3;
            float rm = -1e30f;
#pragma unroll
            for (int j = 0; j < 16; j++) rm = fmaxf(rm, sp[n * 65 + sub * 16 + j]);
            rm = fmaxf(rm, __shfl_xor(rm, 1));
            rm = fmaxf(rm, __shfl_xor(rm, 2));
            float mo = m_i[n];
            float mn = fmaxf(mo, rm);
            float ssum = 0.f;
#pragma unroll
            for (int j = 0; j < 16; j += 2) {
                float e0 = __expf(sp[n * 65 + sub * 16 + j] - mn);
                float e1 = __expf(sp[n * 65 + sub * 16 + j + 1] - mn);
                ssum += e0 + e1;
                *(unsigned int*)(&pb[n * 72 + sub * 16 + j]) = pack2(e0, e1);
            }
            ssum += __shfl_xor(ssum, 1);
            ssum += __shfl_xor(ssum, 2);
            if (sub == 0) {
                float f = __expf(mo - mn);
                fac[n] = f;
                l_i[n] = l_i[n] * f + ssum;
                m_i[n] = mn;
            }
        }
        __syncthreads();
        {
            const bf16x8 bv0 = *(const bf16x8*)(&vt[(w * 16 + c) * 72 + quad * 8]);
            const bf16x8 bv1 = *(const bf16x8*)(&vt[(w * 16 + c) * 72 + quad * 8 + 32]);
#pragma unroll
            for (int qt = 0; qt < 3; qt++) {
                const bf16x8 a0 = *(const bf16x8*)(&pb[(qt * 16 + c) * 72 + quad * 8]);
                const bf16x8 a1 = *(const bf16x8*)(&pb[(qt * 16 + c) * 72 + quad * 8 + 32]);
                f32x4 o = oacc[qt];
                o.x *= fac[qt * 16 + quad * 4 + 0];
                o.y *= fac[qt * 16 + quad * 4 + 1];
                o.z *= fac[qt * 16 + quad * 4 + 2];
                o.w *= fac[qt * 16 + quad * 4 + 3];
                o = __builtin_amdgcn_mfma_f32_16x16x32_bf16(a0, bv0, o, 0, 0, 0);
                o = __builtin_amdgcn_mfma_f32_16x16x32_bf16(a1, bv1, o, 0, 0, 0);
                oacc[qt] = o;
            }
        }
    }
    __syncthreads();
    long long pbase = ((long long)(bh * tiles + tile)) * NTOP * 66;
    if (t < NTOP) {
        part[pbase + t * 66 + 0] = m_i[t];
        part[pbase + t * 66 + 1] = l_i[t];
    }
#pragma unroll
    for (int qt = 0; qt < 3; qt++) {
#pragma unroll
        for (int r = 0; r < 4; r++) {
            int n = qt * 16 + quad * 4 + r;
            if (n < NTOP) part[pbase + (long long)n * 66 + 2 + w * 16 + c] = oacc[qt][r];
        }
    }
}

// ---------------- kF: merge tile partials, scatter rows ----------------------
__global__ __launch_bounds__(256) void kF_combine(const float* __restrict__ part,
                                                  const int* __restrict__ topq,
                                                  float* __restrict__ out, int tiles) {
    int t = threadIdx.x;
    int bh = blockIdx.x;
    int n = blockIdx.y * 4 + (t >> 6);
    int d = t & 63;
    if (n >= NTOP) return;
    long long base = ((long long)(bh * tiles)) * NTOP * 66 + (long long)n * 66;
    const long long ts = (long long)NTOP * 66;
    float M = -1e30f;
    for (int tt = 0; tt < tiles; tt++) M = fmaxf(M, part[base + tt * ts]);
    float L = 0.f, acc = 0.f;
    for (int tt = 0; tt < tiles; tt++) {
        float mt = part[base + tt * ts];
        float wgt = __expf(mt - M);
        L += part[base + tt * ts + 1] * wgt;
        acc += part[base + tt * ts + 2 + d] * wgt;
    }
    int row = topq[bh * NTOP + n];
    out[(((long long)bh << 12) + row) * 64 + d] = acc / L;
}

// ---------------- launch -----------------------------------------------------
extern "C" void kernel_launch(void* const* d_in, const int* in_sizes, int n_in,
                              void* d_out, int out_size, void* d_ws, size_t ws_size,
                              hipStream_t stream) {
    const float* q = (const float*)d_in[0];
    const float* k = (const float*)d_in[1];
    const float* v = (const float*)d_in[2];
    const int* idxs = (const int*)d_in[3];
    float* out = (float*)d_out;

    char* ws = (char*)d_ws;
    float* ws_m = (float*)ws;                 // 131072 f  @ 0
    int* ws_topq = (int*)(ws + 524288);       // 1312 i
    float* ws_vpart = (float*)(ws + 532480);  // 32768 f
    float* ws_part = (float*)(ws + 671744);   // tiles*32*41*66 f

    size_t need16 = 671744ull + 16ull * 32 * NTOP * 66 * 4;
    int tiles = (ws_size >= need16) ? 16 : 8;  // 2 blocks/CU when 16
    int tl = 4096 / tiles;

    kA_scores<<<4096, 256, 0, stream>>>(q, k, idxs, ws_m);
    kB_topk<<<32, 256, 0, stream>>>(ws_m, ws_topq);
    kC1<<<dim3(32, 16), 256, 0, stream>>>(v, ws_vpart);
    kD<<<2048, 256, 0, stream>>>(ws_vpart, out);
    kE_attn<<<dim3(tiles, 32), 256, 0, stream>>>(q, k, v, ws_topq, ws_part, tl);
    kF_combine<<<dim3(32, 11), 256, 0, stream>>>(ws_part, ws_topq, out, tiles);
}